// Round 13
// baseline (176.580 us; speedup 1.0000x reference)
//
#include <hip/hip_runtime.h>
#include <hip/hip_fp16.h>

#define NU_ 100000
#define NI_ 50000
#define E_  600000
#define DD  128
#define NT_ (NU_ + NI_)

// bucketed CSR build: 64-node buckets
#define BKN 64
#define NBKT ((NT_ + 63) >> 6)         // 2344 buckets
#define SBLK 8192                       // edges per scatter block
#define NSB ((E_ + SBLK - 1) / SBLK)    // 74
#define NL (NBKT * NSB)                 // 173456 cells
#define NSCB ((NL + 2047) / 2048)       // 85 scan blocks
// item buckets: mean 64*12=768, sd ~28 -> 1024 = mean + 9.2 sigma
#define MAXE 1024

// prep kernel grid split
#define TOBF_BLKS ((NT_ * DD / 8 + 511) / 512)   // 4688
#define PACK_BLKS 8
#define PREP_BLKS (NSB + TOBF_BLKS + PACK_BLKS)

typedef short bf16x8 __attribute__((ext_vector_type(8)));
typedef float f32x4 __attribute__((ext_vector_type(4)));
typedef unsigned short u16x8 __attribute__((ext_vector_type(8)));

__device__ __forceinline__ unsigned short f2bf(float x) {
  unsigned u = __float_as_uint(x);
  return (unsigned short)((u + 0x7FFFu + ((u >> 16) & 1u)) >> 16);  // RNE
}
__device__ __forceinline__ float bf2f(unsigned short h) {
  return __uint_as_float((unsigned)h << 16);
}
__device__ __forceinline__ unsigned short f2h(float x) {
  return __half_as_ushort(__float2half(x));
}
__device__ __forceinline__ float h2f(unsigned short h) {
  return __half2float(__ushort_as_half(h));
}

// logical scan index L = bkt*NSB + sb  <->  storage idx = sb*NBKT + bkt
__device__ __forceinline__ int sidx(int L) {
  int bkt = L / NSB;
  int sb = L - bkt * NSB;
  return sb * NBKT + bkt;
}

// bf16 A-tile swizzle: 256 B rows, XOR byte bits 4-6 with row bits 0-2
__device__ __forceinline__ int swz(int nn, int b) {
  return nn * 256 + (b ^ ((nn & 7) << 4));
}
// f32 staging swizzle: 512 B rows, same XOR
__device__ __forceinline__ int swz2(int row, int b) {
  return row * 512 + (b ^ ((row & 7) << 4));
}

// ---------------------------------------------------------------------------
// prep: pack (8 blk) + tobf (4688 blk) + hist (74 blk) in one launch.
// ---------------------------------------------------------------------------
__global__ __launch_bounds__(512) void prep_kernel(
    const float* __restrict__ fu, const float* __restrict__ fi,
    const float* __restrict__ W1, const float* __restrict__ W2,
    const int* __restrict__ eu, const int* __restrict__ ei,
    unsigned short* __restrict__ fub, unsigned short* __restrict__ fib,
    unsigned short* __restrict__ Bp, int* __restrict__ hist) {
  __shared__ int cnt[NBKT];  // only used by hist blocks
  int bid = blockIdx.x, tid = threadIdx.x;

  if (bid < NSB) {
    // ---- hist ----
    int sb = bid;
    for (int k = tid; k < NBKT; k += 512) cnt[k] = 0;
    __syncthreads();
#pragma unroll
    for (int j = 0; j < SBLK / 512; j++) {
      int e = sb * SBLK + j * 512 + tid;
      if (e < E_) {
        atomicAdd(&cnt[eu[e] >> 6], 1);
        atomicAdd(&cnt[(NU_ + ei[e]) >> 6], 1);
      }
    }
    __syncthreads();
    for (int k = tid; k < NBKT; k += 512) hist[sb * NBKT + k] = cnt[k];
    return;
  }

  if (bid < NSB + TOBF_BLKS) {
    // ---- f32 -> bf16 feature tables ----
    int t = (bid - NSB) * 512 + tid;
    int nu8 = NU_ * DD / 8;
    int nt8 = NT_ * DD / 8;
    if (t >= nt8) return;
    const float* src;
    unsigned short* dst;
    int k;
    if (t < nu8) { src = fu; dst = fub; k = t; }
    else { src = fi; dst = fib; k = t - nu8; }
    const float4 v0 = reinterpret_cast<const float4*>(src)[k * 2];
    const float4 v1 = reinterpret_cast<const float4*>(src)[k * 2 + 1];
    u16x8 o;
    o[0] = f2bf(v0.x); o[1] = f2bf(v0.y); o[2] = f2bf(v0.z); o[3] = f2bf(v0.w);
    o[4] = f2bf(v1.x); o[5] = f2bf(v1.y); o[6] = f2bf(v1.z); o[7] = f2bf(v1.w);
    reinterpret_cast<u16x8*>(dst)[k] = o;
    return;
  }

  // ---- pack W1,W2 into mfma_f32_16x16x32_bf16 B-fragment order ----
  int t = (bid - NSB - TOBF_BLKS) * 512 + tid;  // 4096 total
  if (t >= 4096) return;
  int w = t >> 11;
  int l = t & 63;
  int kt = (t >> 6) & 3;
  int nt = (t >> 8) & 7;
  const float* W = w ? W2 : W1;
  int n = nt * 16 + (l & 15);
  int k0 = kt * 32 + (l >> 4) * 8;
  unsigned short* dst = Bp + (size_t)t * 8;
#pragma unroll
  for (int j = 0; j < 8; j++) dst[j] = f2bf(W[n * DD + k0 + j]);
}

// ---------------------------------------------------------------------------
// Scan over NL cells in logical (bucket-major) order; per-block exclusive.
// Consumers add bsum[L>>11].
// ---------------------------------------------------------------------------
__global__ __launch_bounds__(256) void scanA_kernel(
    const int* __restrict__ hist, int* __restrict__ off, int* __restrict__ bsum) {
  __shared__ int ts[256];
  int tid = threadIdx.x;
  int base = blockIdx.x * 2048 + tid * 8;
  int v[8];
  int s = 0;
#pragma unroll
  for (int j = 0; j < 8; j++) {
    v[j] = s;
    int L = base + j;
    s += (L < NL) ? hist[sidx(L)] : 0;
  }
  ts[tid] = s;
  __syncthreads();
  for (int ofs = 1; ofs < 256; ofs <<= 1) {
    int add = (tid >= ofs) ? ts[tid - ofs] : 0;
    __syncthreads();
    ts[tid] += add;
    __syncthreads();
  }
  int texcl = ts[tid] - s;
#pragma unroll
  for (int j = 0; j < 8; j++) {
    int L = base + j;
    if (L < NL) off[sidx(L)] = texcl + v[j];
  }
  if (tid == 255) bsum[blockIdx.x] = ts[255];
}

__global__ void scanB_kernel(int* __restrict__ bsum) {
  if (threadIdx.x == 0) {
    int s = 0;
    for (int n = 0; n < NSCB; n++) {
      int t = bsum[n];
      bsum[n] = s;
      s += t;
    }
  }
}

// ---------------------------------------------------------------------------
// Scatter edges into bucket-sorted array. Entry packs EVERYTHING the gather
// needs (kills the nbS dependent load in the fused kernel):
//   .x = neighbor_idx | (fp16bits(snb) << 17)   (snb >= 0 -> sign bit dead)
//   .y = (g_local << 16) | fp16bits(w)
// ---------------------------------------------------------------------------
__global__ __launch_bounds__(512) void scatter_kernel(
    const int* __restrict__ eu, const int* __restrict__ ei,
    const float* __restrict__ nui, const float* __restrict__ niu,
    const float* __restrict__ nu, const float* __restrict__ ni,
    const int* __restrict__ off, const int* __restrict__ bsum,
    int2* __restrict__ binned) {
  __shared__ int cur[NBKT];
  int sb = blockIdx.x, tid = threadIdx.x;
  for (int k = tid; k < NBKT; k += 512)
    cur[k] = off[sb * NBKT + k] + bsum[(k * NSB + sb) >> 11];
  __syncthreads();
#pragma unroll
  for (int j = 0; j < SBLK / 512; j++) {
    int e = sb * SBLK + j * 512 + tid;
    if (e < E_) {
      int u = eu[e], i = ei[e];
      int gi = NU_ + i;
      // entry for dst u, neighbor i: w = niu[e], snb = ni[i]
      unsigned sx1 = (unsigned)i | ((unsigned)f2h(ni[i]) << 17);
      unsigned sy1 = ((unsigned)(u & 63) << 16) | f2h(niu[e]);
      int s1 = atomicAdd(&cur[u >> 6], 1);
      binned[s1] = make_int2((int)sx1, (int)sy1);
      // entry for dst i, neighbor u: w = nui[e], snb = nu[u]
      unsigned sx2 = (unsigned)u | ((unsigned)f2h(nu[u]) << 17);
      unsigned sy2 = ((unsigned)(gi & 63) << 16) | f2h(nui[e]);
      int s2 = atomicAdd(&cur[gi >> 6], 1);
      binned[s2] = make_int2((int)sx2, (int)sy2);
    }
  }
}

// ---------------------------------------------------------------------------
// Fused gather + MFMA GEMM + epilogue, 64-node buckets (4 blocks/CU).
// Gather chain is now: LDS entry -> 256B row read (snb/w unpacked from LDS).
// ---------------------------------------------------------------------------
__global__ __launch_bounds__(512, 8) void fused_kernel(
    const unsigned short* __restrict__ fub, const unsigned short* __restrict__ fib,
    const float* __restrict__ nu, const float* __restrict__ ni,
    const int* __restrict__ off, const int* __restrict__ bsum,
    const int2* __restrict__ binned,
    const unsigned short* __restrict__ Bp,
    const float* __restrict__ b1, const float* __restrict__ b2,
    float* __restrict__ out) {
  __shared__ __align__(16) unsigned short XM[2 * BKN * 128];  // 32 KB
  __shared__ unsigned eidx[MAXE];                             // 4 KB (idx|snb)
  __shared__ unsigned short ew[MAXE];                         // 2 KB (fp16 w)
  __shared__ int csrtmp[128];   // ncnt|ncur; later ssx[64][2]
  __shared__ int nstart[BKN + 1];

  unsigned short* Xs = XM;
  unsigned short* Ms = XM + BKN * 128;
  int* ncnt = csrtmp;
  int* ncur = csrtmp + 64;

  int bkt = blockIdx.x, tid = threadIdx.x;
  int bs = off[bkt] + bsum[(bkt * NSB) >> 11];
  int be = (bkt + 1 < NBKT) ? off[bkt + 1] + bsum[((bkt + 1) * NSB) >> 11] : 2 * E_;
  int cnt = be - bs;
  if (cnt > MAXE) cnt = MAXE;  // 9-sigma safety net

  // ---- per-node CSR in LDS; entries register-carried (cnt <= 1024) ----
  if (tid < BKN) ncnt[tid] = 0;
  __syncthreads();
  int2 e0, e1;
  bool h0 = tid < cnt, h1 = tid + 512 < cnt;
  if (h0) {
    e0 = binned[bs + tid];
    atomicAdd(&ncnt[((unsigned)e0.y >> 16) & 63], 1);
  }
  if (h1) {
    e1 = binned[bs + tid + 512];
    atomicAdd(&ncnt[((unsigned)e1.y >> 16) & 63], 1);
  }
  __syncthreads();

  if (tid < BKN) {  // single-wave shfl scan of 64 counters
    int a = ncnt[tid];
    int incl = a;
#pragma unroll
    for (int ofs = 1; ofs < 64; ofs <<= 1) {
      int t = __shfl_up(incl, ofs);
      if (tid >= ofs) incl += t;
    }
    if (tid == 0) nstart[0] = 0;
    nstart[tid + 1] = incl;
    ncur[tid] = incl - a;
  }
  __syncthreads();

  if (h0) {
    int slot = atomicAdd(&ncur[((unsigned)e0.y >> 16) & 63], 1);
    eidx[slot] = (unsigned)e0.x;
    ew[slot] = (unsigned short)((unsigned)e0.y & 0xFFFFu);
  }
  if (h1) {
    int slot = atomicAdd(&ncur[((unsigned)e1.y >> 16) & 63], 1);
    eidx[slot] = (unsigned)e1.x;
    ew[slot] = (unsigned short)((unsigned)e1.y & 0xFFFFu);
  }
  __syncthreads();

  int wid = tid >> 6, lane = tid & 63;
  int q = lane >> 4, sub = lane & 15;

  // ---- gather phase: 8 nodes/wave, quarter-wave per neighbor ----
  for (int nn = 0; nn < 8; nn++) {
    int gl = wid * 8 + nn;
    int g = bkt * BKN + gl;
    if (g >= NT_) break;
    bool isU = g < NU_;
    const unsigned short* nbF = isU ? fib : fub;
    int cs = nstart[gl], ce = nstart[gl + 1];

    float aA[8] = {0.f, 0.f, 0.f, 0.f, 0.f, 0.f, 0.f, 0.f};
    float aM[8] = {0.f, 0.f, 0.f, 0.f, 0.f, 0.f, 0.f, 0.f};
    for (int j = cs + q; j < ce; j += 4) {
      unsigned ev = eidx[j];
      int idx = ev & 0x1FFFF;
      float snb = h2f((unsigned short)(ev >> 17));
      float w = h2f(ew[j]);
      u16x8 f = *reinterpret_cast<const u16x8*>(nbF + (size_t)idx * DD + sub * 8);
#pragma unroll
      for (int d = 0; d < 8; d++) {
        float r = bf2f((unsigned short)f[d]);
        aA[d] += r * w;
        aM[d] += r * snb;
      }
    }
#pragma unroll
    for (int d = 0; d < 8; d++) {
      aA[d] += __shfl_xor(aA[d], 16);
      aA[d] += __shfl_xor(aA[d], 32);
      aM[d] += __shfl_xor(aM[d], 16);
      aM[d] += __shfl_xor(aM[d], 32);
    }

    int lrow = isU ? g : g - NU_;
    if (q < 2) {
      const unsigned short* ownp = (isU ? fub : fib) + (size_t)lrow * DD + sub * 8;
      u16x8 fo = *reinterpret_cast<const u16x8*>(ownp);
      u16x8 o;
      if (q == 0) {
#pragma unroll
        for (int d = 0; d < 8; d++)
          o[d] = f2bf(bf2f((unsigned short)fo[d]) + aA[d]);
        *reinterpret_cast<u16x8*>((char*)Xs + swz(gl, sub * 16)) = o;
      } else {
        float so = isU ? nu[lrow] : ni[lrow];
#pragma unroll
        for (int d = 0; d < 8; d++)
          o[d] = f2bf(bf2f((unsigned short)fo[d]) * so * aM[d]);
        *reinterpret_cast<u16x8*>((char*)Ms + swz(gl, sub * 16)) = o;
      }
    }
  }
  __syncthreads();

  // ---- MFMA phase: tile t = wid>>1 (rows t*16..+15), cols (wid&1)*64..+63 ----
  int t = wid >> 1, colHalf = wid & 1;
  int gt0 = bkt * BKN + t * 16;
  bool active = gt0 < NT_;  // tail bucket tiles are 16-aligned

  int lm = lane & 15, lh = lane >> 4;
  float h[4][4];
  float inv4[4];
  float (*ssx)[2] = (float(*)[2])csrtmp;  // overlays ncnt/ncur (dead now)

  if (active) {
    f32x4 acc[4];
#pragma unroll
    for (int nt = 0; nt < 4; nt++) acc[nt] = (f32x4){0.f, 0.f, 0.f, 0.f};

#pragma unroll
    for (int kt = 0; kt < 4; kt++) {  // kt-outer keeps VGPR low
      int b = kt * 64 + lh * 16;
      bf16x8 a1 = *reinterpret_cast<const bf16x8*>((char*)Xs + swz(t * 16 + lm, b));
      bf16x8 a2 = *reinterpret_cast<const bf16x8*>((char*)Ms + swz(t * 16 + lm, b));
#pragma unroll
      for (int nt = 0; nt < 4; nt++) {
        int ntp = colHalf * 4 + nt;
        bf16x8 bf1 = *reinterpret_cast<const bf16x8*>(Bp + ((size_t)((0 * 8 + ntp) * 4 + kt) * 64 + lane) * 8);
        acc[nt] = __builtin_amdgcn_mfma_f32_16x16x32_bf16(a1, bf1, acc[nt], 0, 0, 0);
        bf16x8 bf2 = *reinterpret_cast<const bf16x8*>(Bp + ((size_t)((1 * 8 + ntp) * 4 + kt) * 64 + lane) * 8);
        acc[nt] = __builtin_amdgcn_mfma_f32_16x16x32_bf16(a2, bf2, acc[nt], 0, 0, 0);
      }
    }

    // bias -> leaky relu -> partial row sum-of-squares (this col half)
    float ss[4] = {0.f, 0.f, 0.f, 0.f};
#pragma unroll
    for (int nt = 0; nt < 4; nt++) {
      int ntp = colHalf * 4 + nt;
      float bb = b1[ntp * 16 + lm] + b2[ntp * 16 + lm];
#pragma unroll
      for (int r = 0; r < 4; r++) {
        float v = acc[nt][r] + bb;
        v = (v > 0.f) ? v : 0.2f * v;
        h[nt][r] = v;
        ss[r] += v * v;
      }
    }
#pragma unroll
    for (int r = 0; r < 4; r++) {
#pragma unroll
      for (int m = 1; m < 16; m <<= 1) ss[r] += __shfl_xor(ss[r], m);
    }
    if (lm == 0) {
#pragma unroll
      for (int r = 0; r < 4; r++) ssx[t * 16 + lh * 4 + r][colHalf] = ss[r];
    }
  }
  __syncthreads();  // ssx ready; all XM fragment reads complete

  if (active) {
#pragma unroll
    for (int r = 0; r < 4; r++) {
      int row = t * 16 + lh * 4 + r;
      float tot = ssx[row][0] + ssx[row][1];
      inv4[r] = 1.0f / fmaxf(sqrtf(tot), 1e-12f);
    }
    // stage normalized f32 rows in (now-free) XM
    float* stg = reinterpret_cast<float*>(XM);  // [64 rows][512 B]
#pragma unroll
    for (int nt = 0; nt < 4; nt++) {
      int ntp = colHalf * 4 + nt;
#pragma unroll
      for (int r = 0; r < 4; r++) {
        int row = t * 16 + lh * 4 + r;
        *reinterpret_cast<float*>((char*)stg + swz2(row, ntp * 64 + lm * 4)) =
            h[nt][r] * inv4[r];
      }
    }
  }
  __syncthreads();

  // ---- contiguous 32 KB block write ----
  float* stg = reinterpret_cast<float*>(XM);
  int maxrow = NT_ - bkt * BKN;  // <64 only for the tail bucket
  float* ob = out + (size_t)bkt * BKN * DD;
#pragma unroll
  for (int k = 0; k < 4; k++) {
    int c = k * 512 + tid;  // 16B chunk id, 2048 total
    int row = c >> 5;
    if (row < maxrow) {
      f32x4 v = *reinterpret_cast<const f32x4*>((char*)stg + swz2(row, (c & 31) * 16));
      *reinterpret_cast<f32x4*>(ob + (size_t)c * 4) = v;
    }
  }
}

// ---------------------------------------------------------------------------
extern "C" void kernel_launch(void* const* d_in, const int* in_sizes, int n_in,
                              void* d_out, int out_size, void* d_ws, size_t ws_size,
                              hipStream_t stream) {
  const float* fu  = (const float*)d_in[0];
  const float* fi  = (const float*)d_in[1];
  const float* nu  = (const float*)d_in[2];
  const float* ni  = (const float*)d_in[3];
  const float* nui = (const float*)d_in[4];
  const float* niu = (const float*)d_in[5];
  const float* W1  = (const float*)d_in[6];
  const float* b1  = (const float*)d_in[7];
  const float* W2  = (const float*)d_in[8];
  const float* b2  = (const float*)d_in[9];
  const int* eu    = (const int*)d_in[10];
  const int* ei    = (const int*)d_in[11];
  float* out = (float*)d_out;
  char* ws = (char*)d_ws;

  size_t off_b = 0;
  auto alloc = [&](size_t bytes) {
    char* p = ws + off_b;
    off_b += (bytes + 255) & ~(size_t)255;
    return p;
  };
  unsigned short* fub = (unsigned short*)alloc((size_t)NU_ * DD * 2);
  unsigned short* fib = (unsigned short*)alloc((size_t)NI_ * DD * 2);
  unsigned short* Bp  = (unsigned short*)alloc(4096 * 8 * 2);
  int* hist = (int*)alloc((size_t)NL * 4);
  int* offc = (int*)alloc((size_t)NL * 4);
  int* bsum = (int*)alloc(256 * 4);
  int2* binned = (int2*)alloc((size_t)2 * E_ * 8);

  prep_kernel<<<PREP_BLKS, 512, 0, stream>>>(fu, fi, W1, W2, eu, ei,
                                             fub, fib, Bp, hist);
  scanA_kernel<<<NSCB, 256, 0, stream>>>(hist, offc, bsum);
  scanB_kernel<<<1, 64, 0, stream>>>(bsum);
  scatter_kernel<<<NSB, 512, 0, stream>>>(eu, ei, nui, niu, nu, ni,
                                          offc, bsum, binned);

  fused_kernel<<<NBKT, 512, 0, stream>>>(
      fub, fib, nu, ni, offc, bsum, binned, Bp, b1, b2, out);
}

// Round 14
// 164.077 us; speedup vs baseline: 1.0762x; 1.0762x over previous
//
#include <hip/hip_runtime.h>
#include <hip/hip_fp16.h>

#define NU_ 100000
#define NI_ 50000
#define E_  600000
#define DD  128
#define NT_ (NU_ + NI_)

// bucketed CSR build: 64-node buckets
#define BKN 64
#define NBKT ((NT_ + 63) >> 6)         // 2344 buckets
#define SBLK 8192                       // edges per scatter block
#define NSB ((E_ + SBLK - 1) / SBLK)    // 74
#define NL (NBKT * NSB)                 // 173456 cells
#define NSCB ((NL + 2047) / 2048)       // 85 scan blocks
// item buckets: mean 64*12=768, sd ~28 -> 1024 = mean + 9.2 sigma
#define MAXE 1024

// prep kernel grid split
#define TOBF_BLKS ((NT_ * DD / 8 + 511) / 512)   // 4688
#define PACK_BLKS 8
#define PREP_BLKS (NSB + TOBF_BLKS + PACK_BLKS)

typedef short bf16x8 __attribute__((ext_vector_type(8)));
typedef float f32x4 __attribute__((ext_vector_type(4)));
typedef unsigned short u16x8 __attribute__((ext_vector_type(8)));

__device__ __forceinline__ unsigned short f2bf(float x) {
  unsigned u = __float_as_uint(x);
  return (unsigned short)((u + 0x7FFFu + ((u >> 16) & 1u)) >> 16);  // RNE
}
__device__ __forceinline__ float bf2f(unsigned short h) {
  return __uint_as_float((unsigned)h << 16);
}

// logical scan index L = bkt*NSB + sb  <->  storage idx = sb*NBKT + bkt
__device__ __forceinline__ int sidx(int L) {
  int bkt = L / NSB;
  int sb = L - bkt * NSB;
  return sb * NBKT + bkt;
}

// bf16 A-tile swizzle: 256 B rows, XOR byte bits 4-6 with row bits 0-2
__device__ __forceinline__ int swz(int nn, int b) {
  return nn * 256 + (b ^ ((nn & 7) << 4));
}
// f32 staging swizzle: 512 B rows, same XOR
__device__ __forceinline__ int swz2(int row, int b) {
  return row * 512 + (b ^ ((row & 7) << 4));
}

// ---------------------------------------------------------------------------
// prep: pack (8 blk) + tobf (4688 blk) + hist (74 blk) in one launch.
// ---------------------------------------------------------------------------
__global__ __launch_bounds__(512) void prep_kernel(
    const float* __restrict__ fu, const float* __restrict__ fi,
    const float* __restrict__ W1, const float* __restrict__ W2,
    const int* __restrict__ eu, const int* __restrict__ ei,
    unsigned short* __restrict__ fub, unsigned short* __restrict__ fib,
    unsigned short* __restrict__ Bp, int* __restrict__ hist) {
  __shared__ int cnt[NBKT];  // only used by hist blocks
  int bid = blockIdx.x, tid = threadIdx.x;

  if (bid < NSB) {
    // ---- hist ----
    int sb = bid;
    for (int k = tid; k < NBKT; k += 512) cnt[k] = 0;
    __syncthreads();
#pragma unroll
    for (int j = 0; j < SBLK / 512; j++) {
      int e = sb * SBLK + j * 512 + tid;
      if (e < E_) {
        atomicAdd(&cnt[eu[e] >> 6], 1);
        atomicAdd(&cnt[(NU_ + ei[e]) >> 6], 1);
      }
    }
    __syncthreads();
    for (int k = tid; k < NBKT; k += 512) hist[sb * NBKT + k] = cnt[k];
    return;
  }

  if (bid < NSB + TOBF_BLKS) {
    // ---- f32 -> bf16 feature tables ----
    int t = (bid - NSB) * 512 + tid;
    int nu8 = NU_ * DD / 8;
    int nt8 = NT_ * DD / 8;
    if (t >= nt8) return;
    const float* src;
    unsigned short* dst;
    int k;
    if (t < nu8) { src = fu; dst = fub; k = t; }
    else { src = fi; dst = fib; k = t - nu8; }
    const float4 v0 = reinterpret_cast<const float4*>(src)[k * 2];
    const float4 v1 = reinterpret_cast<const float4*>(src)[k * 2 + 1];
    u16x8 o;
    o[0] = f2bf(v0.x); o[1] = f2bf(v0.y); o[2] = f2bf(v0.z); o[3] = f2bf(v0.w);
    o[4] = f2bf(v1.x); o[5] = f2bf(v1.y); o[6] = f2bf(v1.z); o[7] = f2bf(v1.w);
    reinterpret_cast<u16x8*>(dst)[k] = o;
    return;
  }

  // ---- pack W1,W2 into mfma_f32_16x16x32_bf16 B-fragment order ----
  int t = (bid - NSB - TOBF_BLKS) * 512 + tid;  // 4096 total
  if (t >= 4096) return;
  int w = t >> 11;
  int l = t & 63;
  int kt = (t >> 6) & 3;
  int nt = (t >> 8) & 7;
  const float* W = w ? W2 : W1;
  int n = nt * 16 + (l & 15);
  int k0 = kt * 32 + (l >> 4) * 8;
  unsigned short* dst = Bp + (size_t)t * 8;
#pragma unroll
  for (int j = 0; j < 8; j++) dst[j] = f2bf(W[n * DD + k0 + j]);
}

// ---------------------------------------------------------------------------
// Scan over NL cells in logical (bucket-major) order; per-block exclusive.
// bsum holds raw per-block TOTALS; consumers wave-scan it themselves.
// ---------------------------------------------------------------------------
__global__ __launch_bounds__(256) void scanA_kernel(
    const int* __restrict__ hist, int* __restrict__ off, int* __restrict__ bsum) {
  __shared__ int ts[256];
  int tid = threadIdx.x;
  int base = blockIdx.x * 2048 + tid * 8;
  int v[8];
  int s = 0;
#pragma unroll
  for (int j = 0; j < 8; j++) {
    v[j] = s;
    int L = base + j;
    s += (L < NL) ? hist[sidx(L)] : 0;
  }
  ts[tid] = s;
  __syncthreads();
  for (int ofs = 1; ofs < 256; ofs <<= 1) {
    int add = (tid >= ofs) ? ts[tid - ofs] : 0;
    __syncthreads();
    ts[tid] += add;
    __syncthreads();
  }
  int texcl = ts[tid] - s;
#pragma unroll
  for (int j = 0; j < 8; j++) {
    int L = base + j;
    if (L < NL) off[sidx(L)] = texcl + v[j];
  }
  if (tid == 255) bsum[blockIdx.x] = ts[255];
}

// ---------------------------------------------------------------------------
// Scatter edges into bucket-sorted array. Wave 0 computes the bsum exclusive
// prefix in-block (scanB folded away).
// entry.x = (g_local<<20) | neighbor_idx ; entry.y = weight bits
// ---------------------------------------------------------------------------
__global__ __launch_bounds__(512) void scatter_kernel(
    const int* __restrict__ eu, const int* __restrict__ ei,
    const float* __restrict__ nui, const float* __restrict__ niu,
    const int* __restrict__ off, const int* __restrict__ bsum,
    int2* __restrict__ binned) {
  __shared__ int cur[NBKT];
  __shared__ int bpre[128];
  int sb = blockIdx.x, tid = threadIdx.x;

  if (tid < 64) {  // exclusive prefix of bsum[0..NSCB)
    int i0 = 2 * tid, i1 = 2 * tid + 1;
    int a = (i0 < NSCB) ? bsum[i0] : 0;
    int b = (i1 < NSCB) ? bsum[i1] : 0;
    int p = a + b;
    int incl = p;
#pragma unroll
    for (int ofs = 1; ofs < 64; ofs <<= 1) {
      int t = __shfl_up(incl, ofs);
      if (tid >= ofs) incl += t;
    }
    int excl = incl - p;
    bpre[i0] = excl;
    bpre[i1] = excl + a;
  }
  __syncthreads();

  for (int k = tid; k < NBKT; k += 512)
    cur[k] = off[sb * NBKT + k] + bpre[(k * NSB + sb) >> 11];
  __syncthreads();
#pragma unroll
  for (int j = 0; j < SBLK / 512; j++) {
    int e = sb * SBLK + j * 512 + tid;
    if (e < E_) {
      int u = eu[e], i = ei[e];
      int gi = NU_ + i;
      int s1 = atomicAdd(&cur[u >> 6], 1);
      binned[s1] = make_int2(((u & 63) << 20) | i, __float_as_int(niu[e]));
      int s2 = atomicAdd(&cur[gi >> 6], 1);
      binned[s2] = make_int2(((gi & 63) << 20) | u, __float_as_int(nui[e]));
    }
  }
}

// ---------------------------------------------------------------------------
// Fused gather + MFMA GEMM + epilogue, 64-node buckets (4 blocks/CU).
// Wave 0 computes the bsum prefix into eidx[0..127] (reused later for CSR).
// ---------------------------------------------------------------------------
__global__ __launch_bounds__(512, 8) void fused_kernel(
    const unsigned short* __restrict__ fub, const unsigned short* __restrict__ fib,
    const float* __restrict__ nu, const float* __restrict__ ni,
    const int* __restrict__ off, const int* __restrict__ bsum,
    const int2* __restrict__ binned,
    const unsigned short* __restrict__ Bp,
    const float* __restrict__ b1, const float* __restrict__ b2,
    float* __restrict__ out) {
  __shared__ __align__(16) unsigned short XM[2 * BKN * 128];  // 32 KB
  __shared__ int eidx[MAXE];                                  // 4 KB (bpre, then idx)
  __shared__ unsigned short ew[MAXE];                         // 2 KB (fp16 w)
  __shared__ int csrtmp[128];   // ncnt|ncur; later ssx[64][2]
  __shared__ int nstart[BKN + 1];

  unsigned short* Xs = XM;
  unsigned short* Ms = XM + BKN * 128;
  int* ncnt = csrtmp;
  int* ncur = csrtmp + 64;

  int bkt = blockIdx.x, tid = threadIdx.x;

  // ---- phase 0: wave0 scans bsum into eidx[0..127]; tids 64-127 zero ncnt ----
  if (tid < 64) {
    int i0 = 2 * tid, i1 = 2 * tid + 1;
    int a = (i0 < NSCB) ? bsum[i0] : 0;
    int b = (i1 < NSCB) ? bsum[i1] : 0;
    int p = a + b;
    int incl = p;
#pragma unroll
    for (int ofs = 1; ofs < 64; ofs <<= 1) {
      int t = __shfl_up(incl, ofs);
      if (tid >= ofs) incl += t;
    }
    int excl = incl - p;
    eidx[i0] = excl;
    eidx[i1] = excl + a;
  } else if (tid < 128) {
    csrtmp[tid - 64] = 0;  // zero ncnt
  }
  __syncthreads();

  int bs = off[bkt] + eidx[(bkt * NSB) >> 11];
  int be = (bkt + 1 < NBKT) ? off[bkt + 1] + eidx[((bkt + 1) * NSB) >> 11] : 2 * E_;
  int cnt = be - bs;
  if (cnt > MAXE) cnt = MAXE;  // 9-sigma safety net

  // ---- per-node CSR in LDS; entries register-carried (cnt <= 1024) ----
  int2 e0, e1;
  bool h0 = tid < cnt, h1 = tid + 512 < cnt;
  if (h0) {
    e0 = binned[bs + tid];
    atomicAdd(&ncnt[(e0.x >> 20) & 63], 1);
  }
  if (h1) {
    e1 = binned[bs + tid + 512];
    atomicAdd(&ncnt[(e1.x >> 20) & 63], 1);
  }
  __syncthreads();

  if (tid < BKN) {  // single-wave shfl scan of 64 counters
    int a = ncnt[tid];
    int incl = a;
#pragma unroll
    for (int ofs = 1; ofs < 64; ofs <<= 1) {
      int t = __shfl_up(incl, ofs);
      if (tid >= ofs) incl += t;
    }
    if (tid == 0) nstart[0] = 0;
    nstart[tid + 1] = incl;
    ncur[tid] = incl - a;
  }
  __syncthreads();

  if (h0) {
    int slot = atomicAdd(&ncur[(e0.x >> 20) & 63], 1);
    eidx[slot] = e0.x & 0xFFFFF;
    ew[slot] = __half_as_ushort(__float2half(__int_as_float(e0.y)));
  }
  if (h1) {
    int slot = atomicAdd(&ncur[(e1.x >> 20) & 63], 1);
    eidx[slot] = e1.x & 0xFFFFF;
    ew[slot] = __half_as_ushort(__float2half(__int_as_float(e1.y)));
  }
  __syncthreads();

  int wid = tid >> 6, lane = tid & 63;
  int q = lane >> 4, sub = lane & 15;

  // ---- gather phase: 8 nodes/wave, quarter-wave per neighbor ----
  for (int nn = 0; nn < 8; nn++) {
    int gl = wid * 8 + nn;
    int g = bkt * BKN + gl;
    if (g >= NT_) break;
    bool isU = g < NU_;
    const unsigned short* nbF = isU ? fib : fub;
    const float* nbS = isU ? ni : nu;
    int cs = nstart[gl], ce = nstart[gl + 1];

    float aA[8] = {0.f, 0.f, 0.f, 0.f, 0.f, 0.f, 0.f, 0.f};
    float aM[8] = {0.f, 0.f, 0.f, 0.f, 0.f, 0.f, 0.f, 0.f};
    for (int j = cs + q; j < ce; j += 4) {
      int idx = eidx[j];
      float w = __half2float(__ushort_as_half(ew[j]));
      float snb = nbS[idx];
      u16x8 f = *reinterpret_cast<const u16x8*>(nbF + (size_t)idx * DD + sub * 8);
#pragma unroll
      for (int d = 0; d < 8; d++) {
        float r = bf2f((unsigned short)f[d]);
        aA[d] += r * w;
        aM[d] += r * snb;
      }
    }
#pragma unroll
    for (int d = 0; d < 8; d++) {
      aA[d] += __shfl_xor(aA[d], 16);
      aA[d] += __shfl_xor(aA[d], 32);
      aM[d] += __shfl_xor(aM[d], 16);
      aM[d] += __shfl_xor(aM[d], 32);
    }

    int lrow = isU ? g : g - NU_;
    if (q < 2) {
      const unsigned short* ownp = (isU ? fub : fib) + (size_t)lrow * DD + sub * 8;
      u16x8 fo = *reinterpret_cast<const u16x8*>(ownp);
      u16x8 o;
      if (q == 0) {
#pragma unroll
        for (int d = 0; d < 8; d++)
          o[d] = f2bf(bf2f((unsigned short)fo[d]) + aA[d]);
        *reinterpret_cast<u16x8*>((char*)Xs + swz(gl, sub * 16)) = o;
      } else {
        float so = isU ? nu[lrow] : ni[lrow];
#pragma unroll
        for (int d = 0; d < 8; d++)
          o[d] = f2bf(bf2f((unsigned short)fo[d]) * so * aM[d]);
        *reinterpret_cast<u16x8*>((char*)Ms + swz(gl, sub * 16)) = o;
      }
    }
  }
  __syncthreads();

  // ---- MFMA phase: tile t = wid>>1 (rows t*16..+15), cols (wid&1)*64..+63 ----
  int t = wid >> 1, colHalf = wid & 1;
  int gt0 = bkt * BKN + t * 16;
  bool active = gt0 < NT_;  // tail bucket tiles are 16-aligned

  int lm = lane & 15, lh = lane >> 4;
  float h[4][4];
  float inv4[4];
  float (*ssx)[2] = (float(*)[2])csrtmp;  // overlays ncnt/ncur (dead now)

  if (active) {
    f32x4 acc[4];
#pragma unroll
    for (int nt = 0; nt < 4; nt++) acc[nt] = (f32x4){0.f, 0.f, 0.f, 0.f};

#pragma unroll
    for (int kt = 0; kt < 4; kt++) {  // kt-outer keeps VGPR low
      int b = kt * 64 + lh * 16;
      bf16x8 a1 = *reinterpret_cast<const bf16x8*>((char*)Xs + swz(t * 16 + lm, b));
      bf16x8 a2 = *reinterpret_cast<const bf16x8*>((char*)Ms + swz(t * 16 + lm, b));
#pragma unroll
      for (int nt = 0; nt < 4; nt++) {
        int ntp = colHalf * 4 + nt;
        bf16x8 bf1 = *reinterpret_cast<const bf16x8*>(Bp + ((size_t)((0 * 8 + ntp) * 4 + kt) * 64 + lane) * 8);
        acc[nt] = __builtin_amdgcn_mfma_f32_16x16x32_bf16(a1, bf1, acc[nt], 0, 0, 0);
        bf16x8 bf2 = *reinterpret_cast<const bf16x8*>(Bp + ((size_t)((1 * 8 + ntp) * 4 + kt) * 64 + lane) * 8);
        acc[nt] = __builtin_amdgcn_mfma_f32_16x16x32_bf16(a2, bf2, acc[nt], 0, 0, 0);
      }
    }

    // bias -> leaky relu -> partial row sum-of-squares (this col half)
    float ss[4] = {0.f, 0.f, 0.f, 0.f};
#pragma unroll
    for (int nt = 0; nt < 4; nt++) {
      int ntp = colHalf * 4 + nt;
      float bb = b1[ntp * 16 + lm] + b2[ntp * 16 + lm];
#pragma unroll
      for (int r = 0; r < 4; r++) {
        float v = acc[nt][r] + bb;
        v = (v > 0.f) ? v : 0.2f * v;
        h[nt][r] = v;
        ss[r] += v * v;
      }
    }
#pragma unroll
    for (int r = 0; r < 4; r++) {
#pragma unroll
      for (int m = 1; m < 16; m <<= 1) ss[r] += __shfl_xor(ss[r], m);
    }
    if (lm == 0) {
#pragma unroll
      for (int r = 0; r < 4; r++) ssx[t * 16 + lh * 4 + r][colHalf] = ss[r];
    }
  }
  __syncthreads();  // ssx ready; all XM fragment reads complete

  if (active) {
#pragma unroll
    for (int r = 0; r < 4; r++) {
      int row = t * 16 + lh * 4 + r;
      float tot = ssx[row][0] + ssx[row][1];
      inv4[r] = 1.0f / fmaxf(sqrtf(tot), 1e-12f);
    }
    // stage normalized f32 rows in (now-free) XM
    float* stg = reinterpret_cast<float*>(XM);  // [64 rows][512 B]
#pragma unroll
    for (int nt = 0; nt < 4; nt++) {
      int ntp = colHalf * 4 + nt;
#pragma unroll
      for (int r = 0; r < 4; r++) {
        int row = t * 16 + lh * 4 + r;
        *reinterpret_cast<float*>((char*)stg + swz2(row, ntp * 64 + lm * 4)) =
            h[nt][r] * inv4[r];
      }
    }
  }
  __syncthreads();

  // ---- contiguous 32 KB block write ----
  float* stg = reinterpret_cast<float*>(XM);
  int maxrow = NT_ - bkt * BKN;  // <64 only for the tail bucket
  float* ob = out + (size_t)bkt * BKN * DD;
#pragma unroll
  for (int k = 0; k < 4; k++) {
    int c = k * 512 + tid;  // 16B chunk id, 2048 total
    int row = c >> 5;
    if (row < maxrow) {
      f32x4 v = *reinterpret_cast<const f32x4*>((char*)stg + swz2(row, (c & 31) * 16));
      *reinterpret_cast<f32x4*>(ob + (size_t)c * 4) = v;
    }
  }
}

// ---------------------------------------------------------------------------
extern "C" void kernel_launch(void* const* d_in, const int* in_sizes, int n_in,
                              void* d_out, int out_size, void* d_ws, size_t ws_size,
                              hipStream_t stream) {
  const float* fu  = (const float*)d_in[0];
  const float* fi  = (const float*)d_in[1];
  const float* nu  = (const float*)d_in[2];
  const float* ni  = (const float*)d_in[3];
  const float* nui = (const float*)d_in[4];
  const float* niu = (const float*)d_in[5];
  const float* W1  = (const float*)d_in[6];
  const float* b1  = (const float*)d_in[7];
  const float* W2  = (const float*)d_in[8];
  const float* b2  = (const float*)d_in[9];
  const int* eu    = (const int*)d_in[10];
  const int* ei    = (const int*)d_in[11];
  float* out = (float*)d_out;
  char* ws = (char*)d_ws;

  size_t off_b = 0;
  auto alloc = [&](size_t bytes) {
    char* p = ws + off_b;
    off_b += (bytes + 255) & ~(size_t)255;
    return p;
  };
  unsigned short* fub = (unsigned short*)alloc((size_t)NU_ * DD * 2);
  unsigned short* fib = (unsigned short*)alloc((size_t)NI_ * DD * 2);
  unsigned short* Bp  = (unsigned short*)alloc(4096 * 8 * 2);
  int* hist = (int*)alloc((size_t)NL * 4);
  int* offc = (int*)alloc((size_t)NL * 4);
  int* bsum = (int*)alloc(256 * 4);
  int2* binned = (int2*)alloc((size_t)2 * E_ * 8);

  prep_kernel<<<PREP_BLKS, 512, 0, stream>>>(fu, fi, W1, W2, eu, ei,
                                             fub, fib, Bp, hist);
  scanA_kernel<<<NSCB, 256, 0, stream>>>(hist, offc, bsum);
  scatter_kernel<<<NSB, 512, 0, stream>>>(eu, ei, nui, niu, offc, bsum, binned);

  fused_kernel<<<NBKT, 512, 0, stream>>>(
      fub, fib, nu, ni, offc, bsum, binned, Bp, b1, b2, out);
}